// Round 5
// baseline (532.284 us; speedup 1.0000x reference)
//
#include <hip/hip_runtime.h>
#include <math.h>

#define MTOT 32768   // BATCH * SEQ_LEN
#define KD 512       // INPUT_DIM
#define HD 512       // HIDDEN_DIM
#define NB 8         // BATCH
#define TS 4096      // SEQ_LEN

typedef __attribute__((ext_vector_type(8))) short bf16x8;
typedef __attribute__((ext_vector_type(4))) float f32x4;
typedef __attribute__((ext_vector_type(4))) unsigned short us4;

// async 16B global->LDS copy: lane l writes lds_base + l*16
#define GLD16(gsrc, ldst) __builtin_amdgcn_global_load_lds( \
    (const __attribute__((address_space(1))) void*)(gsrc),   \
    (__attribute__((address_space(3))) void*)(ldst), 16, 0, 0)

__device__ __forceinline__ unsigned short f2bf(float f) {
    unsigned u = __float_as_uint(f);
    return (unsigned short)((u + 0x7FFFu + ((u >> 16) & 1u)) >> 16);
}
__device__ __forceinline__ float bf2f(unsigned short u) {
    return __uint_as_float(((unsigned)u) << 16);
}

// ---------------- cast kernel: x -> x16, {B,G,C,D} -> w16; zero flags --------
__global__ __launch_bounds__(256) void cast_all(
    const float* __restrict__ x, const float* __restrict__ B,
    const float* __restrict__ G, const float* __restrict__ C,
    const float* __restrict__ D,
    unsigned short* __restrict__ x16, unsigned short* __restrict__ w16,
    unsigned* __restrict__ flags)   // 2048 flags + 1 vid counter
{
    const int blk = blockIdx.x;
    if (blk == 0) {
        for (int i = threadIdx.x; i < 2049; i += 256) flags[i] = 0u;
    }
    const float* src;
    unsigned short* dst;
    int i;
    if (blk < (MTOT * KD / 1024)) {
        src = x; dst = x16;
        i = blk * 1024 + threadIdx.x * 4;
    } else {
        const int r = blk - (MTOT * KD / 1024);
        const int mat = r >> 8;                    // 256 blocks per matrix
        src = (mat == 0) ? B : (mat == 1) ? G : (mat == 2) ? C : D;
        dst = w16 + (size_t)mat * (HD * KD);
        i = (r & 255) * 1024 + threadIdx.x * 4;
    }
    float4 v = *(const float4*)(src + i);
    us4 o; o.x = f2bf(v.x); o.y = f2bf(v.y); o.z = f2bf(v.z); o.w = f2bf(v.w);
    *(us4*)(dst + i) = o;
}

// ---------------- fused input GEMMs (B,G) + full scan -> hs16 ----------------
// block 128(M) x 64(N), BK=64; 4 waves of 64x32; block = 2 chunks of 64 steps.
// Decoupled lookback over the <=31 predecessor blocks in the same (batch,ny)
// chain gives the entry state; in-register replay writes hs (bf16) directly.
__global__ __launch_bounds__(256, 3) void in_gemm_scan(
    const short* __restrict__ xb, const short* __restrict__ wmat,  // B, G packed
    const float* __restrict__ Avec, const float* __restrict__ bias_h,
    unsigned short* __restrict__ hs_out,
    unsigned long long* __restrict__ payload,   // [2048][64] (P,S) f32 pairs
    unsigned* __restrict__ flags)               // [2048] + counter at [2048]
{
    __shared__ __align__(16) char smem[(128 * 64 + 2 * 64 * 64) * 2];  // 32 KiB
    short* Xs  = (short*)smem;                 // 128x64 staging; reused as hsT[128][72]
    short* Ws0 = Xs + 128 * 64;                // B tile 64x64
    short* Ws1 = Ws0 + 64 * 64;                // G tile 64x64
    short* hsT = (short*)smem;                 // [128][72] = 18432 B, reuse after K-loop
    __shared__ float2 chunkAgg[2][64];
    __shared__ float Eblk[64];
    __shared__ unsigned vid_s;

    const int tid = threadIdx.x;
    if (tid == 0) vid_s = atomicAdd(flags + 2048, 1u);
    __syncthreads();
    const unsigned vid = vid_s;
    const int mxG = vid >> 3;                  // 0..255  (m-tile, in-order per chain)
    const int ny  = vid & 7;                   // 0..7    (n-tile)
    const int m0 = mxG * 128;
    const int n0 = ny * 64;
    const int batch = mxG >> 5;                // 32 m-tiles per batch
    const int pos   = mxG & 31;                // chain position
    const int base_f = ny * 256 + batch * 32;  // flag/payload chain base

    const int w = tid >> 6, l = tid & 63;
    const int wm = (w & 1) * 64;               // chunk select (0 or 1)
    const int wn = (w >> 1) * 32;

    int xsrc[4], xdst[4];
    #pragma unroll
    for (int j = 0; j < 4; ++j) {
        const int s = (w * 4 + j) * 64 + l;
        const int r = s >> 3, g = (s & 7) ^ (r & 7);
        xsrc[j] = (m0 + r) * KD + g * 8;
        xdst[j] = (w * 4 + j) * 64 * 8;
    }
    int wsrc[2], wdst[2];
    #pragma unroll
    for (int j = 0; j < 2; ++j) {
        const int s = (w * 2 + j) * 64 + l;
        const int r = s >> 3, g = (s & 7) ^ (r & 7);
        wsrc[j] = (n0 + r) * KD + g * 8;
        wdst[j] = (w * 2 + j) * 64 * 8;
    }

    f32x4 acc[2][4][2];
    #pragma unroll
    for (int a = 0; a < 2; ++a)
        #pragma unroll
        for (int i = 0; i < 4; ++i)
            #pragma unroll
            for (int j = 0; j < 2; ++j) acc[a][i][j] = (f32x4)0.0f;

    for (int kk = 0; kk < KD; kk += 64) {
        __syncthreads();
        #pragma unroll
        for (int j = 0; j < 4; ++j) GLD16(xb + xsrc[j] + kk, Xs + xdst[j]);
        #pragma unroll
        for (int j = 0; j < 2; ++j) {
            GLD16(wmat + wsrc[j] + kk, Ws0 + wdst[j]);
            GLD16(wmat + (size_t)(HD * KD) + wsrc[j] + kk, Ws1 + wdst[j]);
        }
        __syncthreads();
        #pragma unroll
        for (int kc = 0; kc < 2; ++kc) {
            const int g = kc * 4 + (l >> 4);
            bf16x8 af[4];
            #pragma unroll
            for (int mt = 0; mt < 4; ++mt) {
                const int r = wm + mt * 16 + (l & 15);
                af[mt] = *(const bf16x8*)(Xs + r * 64 + ((g ^ (r & 7)) * 8));
            }
            #pragma unroll
            for (int nt = 0; nt < 2; ++nt) {
                const int r = wn + nt * 16 + (l & 15);
                const int off = r * 64 + ((g ^ (r & 7)) * 8);
                const bf16x8 bfB = *(const bf16x8*)(Ws0 + off);
                const bf16x8 bfG = *(const bf16x8*)(Ws1 + off);
                #pragma unroll
                for (int mt = 0; mt < 4; ++mt) {
                    acc[0][mt][nt] = __builtin_amdgcn_mfma_f32_16x16x32_bf16(
                        af[mt], bfB, acc[0][mt][nt], 0, 0, 0);
                    acc[1][mt][nt] = __builtin_amdgcn_mfma_f32_16x16x32_bf16(
                        af[mt], bfG, acc[1][mt][nt], 0, 0, 0);
                }
            }
        }
    }

    // ---- pass A: gate math, pack (a,b), chunk aggregates ----
    // C/D layout: col = l&15, row = (l>>4)*4 + reg
    const int q  = l >> 4;
    const int cl = l & 15;
    unsigned ab_pack[2][16];
    #pragma unroll
    for (int nt = 0; nt < 2; ++nt) {
        const int n = n0 + wn + nt * 16 + cl;
        const float An1 = 1.0f - Avec[n];
        const float bh  = bias_h[n];
        float Pc = 1.0f, Sc = 0.0f;
        #pragma unroll
        for (int mt = 0; mt < 4; ++mt) {
            float Pl = 1.0f, Sl = 0.0f;
            #pragma unroll
            for (int r = 0; r < 4; ++r) {
                const float vB = acc[0][mt][nt][r];
                const float vG = acc[1][mt][nt][r];
                float g = __builtin_amdgcn_rcpf(1.0f + __expf(-vG));
                g = fminf(fmaxf(g, 0.05f), 0.95f);
                const unsigned short su = f2bf(g * An1);
                const unsigned short bu = f2bf(g * (vB + bh));
                ab_pack[nt][mt * 4 + r] = (unsigned)su | ((unsigned)bu << 16);
                const float a = 1.0f - bf2f(su);
                Sl = fmaf(a, Sl, bf2f(bu));
                Pl *= a;
            }
            float Pm = 1.0f, Sm = 0.0f;
            #pragma unroll
            for (int k = 0; k < 4; ++k) {
                const float Pk = __shfl(Pl, cl + 16 * k, 64);
                const float Sk = __shfl(Sl, cl + 16 * k, 64);
                Sm = fmaf(Pk, Sm, Sk);
                Pm *= Pk;
            }
            Sc = fmaf(Pm, Sc, Sm);
            Pc *= Pm;
        }
        if (q == 0) chunkAgg[w & 1][wn + nt * 16 + cl] = make_float2(Pc, Sc);
    }
    __syncthreads();

    // ---- publish block aggregate (device-scope) ----
    if (tid < 64) {
        const float2 c0 = chunkAgg[0][tid], c1 = chunkAgg[1][tid];
        union { float2 f; unsigned long long u; } cv;
        cv.f = make_float2(c1.x * c0.x, fmaf(c1.x, c0.y, c1.y));
        __hip_atomic_store(&payload[(size_t)(base_f + pos) * 64 + tid], cv.u,
                           __ATOMIC_RELAXED, __HIP_MEMORY_SCOPE_AGENT);
    }
    __syncthreads();
    if (tid == 0)
        __hip_atomic_store(&flags[base_f + pos], 1u,
                           __ATOMIC_RELEASE, __HIP_MEMORY_SCOPE_AGENT);

    // ---- lookback: entry state = compose aggs of preds pos-1 .. 0 ----
    if (tid < 64) {
        float Pa = 1.0f, Sa = 0.0f;
        for (int p = pos - 1; p >= 0; --p) {
            int guard = 0;
            while (__hip_atomic_load(&flags[base_f + p], __ATOMIC_ACQUIRE,
                                     __HIP_MEMORY_SCOPE_AGENT) == 0u) {
                __builtin_amdgcn_s_sleep(8);
                if (++guard > (1 << 22)) break;   // safety: never hang the bench
            }
            union { float2 f; unsigned long long u; } cv;
            cv.u = __hip_atomic_load(&payload[(size_t)(base_f + p) * 64 + tid],
                                     __ATOMIC_RELAXED, __HIP_MEMORY_SCOPE_AGENT);
            Sa = fmaf(Pa, cv.f.y, Sa);   // composed := composed ∘ A_p
            Pa *= cv.f.x;
        }
        Eblk[tid] = Sa;                  // entry h for chunk 2*pos (h0 = 0)
    }
    __syncthreads();

    // ---- pass B: in-register replay, hs -> LDS (staging LDS reused) ----
    #pragma unroll
    for (int nt = 0; nt < 2; ++nt) {
        const int hcol = wn + nt * 16 + cl;
        float E_run = Eblk[hcol];
        if (w & 1) {                      // second chunk: advance past chunk 0
            const float2 c0 = chunkAgg[0][hcol];
            E_run = fmaf(c0.x, E_run, c0.y);
        }
        #pragma unroll
        for (int mt = 0; mt < 4; ++mt) {
            float av[4], bv[4];
            float Pl = 1.0f, Sl = 0.0f;
            #pragma unroll
            for (int r = 0; r < 4; ++r) {
                const unsigned pk = ab_pack[nt][mt * 4 + r];
                av[r] = 1.0f - bf2f((unsigned short)(pk & 0xFFFFu));
                bv[r] = bf2f((unsigned short)(pk >> 16));
                Sl = fmaf(av[r], Sl, bv[r]);
                Pl *= av[r];
            }
            float Pacc = 1.0f, Sacc = 0.0f, Pq = 1.0f, Sq = 0.0f;
            #pragma unroll
            for (int k = 0; k < 4; ++k) {
                const float Pk = __shfl(Pl, cl + 16 * k, 64);
                const float Sk = __shfl(Sl, cl + 16 * k, 64);
                if (k == q) { Pq = Pacc; Sq = Sacc; }
                Sacc = fmaf(Pk, Sacc, Sk);
                Pacc *= Pk;
            }
            float hv = fmaf(Pq, E_run, Sq);      // entry to this lane's 4 steps
            #pragma unroll
            for (int r = 0; r < 4; ++r) {
                hv = fmaf(av[r], hv, bv[r]);
                hsT[(wm + mt * 16 + q * 4 + r) * 72 + hcol] = (short)f2bf(hv);
            }
            E_run = fmaf(Pacc, E_run, Sacc);
        }
    }
    __syncthreads();

    // ---- coalesced 16B stores of the 128x64 hs tile ----
    #pragma unroll
    for (int it = 0; it < 4; ++it) {
        const int o = it * 2048 + tid * 8;       // in shorts
        const int row = o >> 6, col = o & 63;
        const bf16x8 v = *(const bf16x8*)(hsT + row * 72 + col);
        *(bf16x8*)(hs_out + (size_t)(m0 + row) * HD + n0 + col) = v;
    }
}

// ---------------- dual-A output GEMM: y = (hs@C^T + x@D^T + bias_y)*scale ----
__global__ __launch_bounds__(256, 2) void out_gemm_dual(
    const short* __restrict__ hs, const short* __restrict__ xb,
    const short* __restrict__ Cb, const short* __restrict__ Db,
    const float* __restrict__ bias_y, float* __restrict__ y)
{
    __shared__ __align__(16) short Hs[128 * 64];
    __shared__ __align__(16) short Xs2[128 * 64];
    __shared__ __align__(16) short Cs[128 * 64];
    __shared__ __align__(16) short Ds[128 * 64];
    const int tid = threadIdx.x;
    const int w = tid >> 6, l = tid & 63;
    const int m0 = blockIdx.x * 128;
    const int n0 = blockIdx.y * 128;
    const int wm = (w & 1) * 64;
    const int wn = (w >> 1) * 64;

    int src_m[4], src_n[4], dst_s[4];
    #pragma unroll
    for (int j = 0; j < 4; ++j) {
        const int s = (w * 4 + j) * 64 + l;
        const int r = s >> 3, g = (s & 7) ^ (r & 7);
        src_m[j] = (m0 + r) * HD + g * 8;
        src_n[j] = (n0 + r) * HD + g * 8;
        dst_s[j] = (w * 4 + j) * 64 * 8;
    }

    f32x4 acc[4][4];
    #pragma unroll
    for (int i = 0; i < 4; ++i)
        #pragma unroll
        for (int j = 0; j < 4; ++j) acc[i][j] = (f32x4)0.0f;

    for (int kk = 0; kk < HD; kk += 64) {
        __syncthreads();
        #pragma unroll
        for (int j = 0; j < 4; ++j) {
            GLD16(hs + src_m[j] + kk, Hs  + dst_s[j]);
            GLD16(xb + src_m[j] + kk, Xs2 + dst_s[j]);
            GLD16(Cb + src_n[j] + kk, Cs  + dst_s[j]);
            GLD16(Db + src_n[j] + kk, Ds  + dst_s[j]);
        }
        __syncthreads();
        #pragma unroll
        for (int kc = 0; kc < 2; ++kc) {
            const int g = kc * 4 + (l >> 4);
            {   // hs @ C^T
                bf16x8 af[4], bfv[4];
                #pragma unroll
                for (int t = 0; t < 4; ++t) {
                    const int ra = wm + t * 16 + (l & 15);
                    af[t] = *(const bf16x8*)(Hs + ra * 64 + ((g ^ (ra & 7)) * 8));
                    const int rb = wn + t * 16 + (l & 15);
                    bfv[t] = *(const bf16x8*)(Cs + rb * 64 + ((g ^ (rb & 7)) * 8));
                }
                #pragma unroll
                for (int mt = 0; mt < 4; ++mt)
                    #pragma unroll
                    for (int nt = 0; nt < 4; ++nt)
                        acc[mt][nt] = __builtin_amdgcn_mfma_f32_16x16x32_bf16(
                            af[mt], bfv[nt], acc[mt][nt], 0, 0, 0);
            }
            {   // x @ D^T
                bf16x8 af[4], bfv[4];
                #pragma unroll
                for (int t = 0; t < 4; ++t) {
                    const int ra = wm + t * 16 + (l & 15);
                    af[t] = *(const bf16x8*)(Xs2 + ra * 64 + ((g ^ (ra & 7)) * 8));
                    const int rb = wn + t * 16 + (l & 15);
                    bfv[t] = *(const bf16x8*)(Ds + rb * 64 + ((g ^ (rb & 7)) * 8));
                }
                #pragma unroll
                for (int mt = 0; mt < 4; ++mt)
                    #pragma unroll
                    for (int nt = 0; nt < 4; ++nt)
                        acc[mt][nt] = __builtin_amdgcn_mfma_f32_16x16x32_bf16(
                            af[mt], bfv[nt], acc[mt][nt], 0, 0, 0);
            }
        }
    }

    const float scale = 0.04419417382415922f;  // 1/sqrt(512)
    #pragma unroll
    for (int nt = 0; nt < 4; ++nt) {
        const int n = n0 + wn + nt * 16 + (l & 15);
        const float by = bias_y[n];
        #pragma unroll
        for (int mt = 0; mt < 4; ++mt) {
            #pragma unroll
            for (int r = 0; r < 4; ++r) {
                const int m = m0 + wm + mt * 16 + (l >> 4) * 4 + r;
                y[(size_t)m * HD + n] = (acc[mt][nt][r] + by) * scale;
            }
        }
    }
}

extern "C" void kernel_launch(void* const* d_in, const int* in_sizes, int n_in,
                              void* d_out, int out_size, void* d_ws, size_t ws_size,
                              hipStream_t stream) {
    const float* x      = (const float*)d_in[0];
    const float* Avec   = (const float*)d_in[1];
    const float* Bw     = (const float*)d_in[2];
    const float* Cw     = (const float*)d_in[3];
    const float* Dw     = (const float*)d_in[4];
    const float* Wg     = (const float*)d_in[5];
    const float* bias_h = (const float*)d_in[6];
    const float* bias_y = (const float*)d_in[7];
    float* y = (float*)d_out;

    unsigned short* x16  = (unsigned short*)d_ws;                      // 32 MiB
    unsigned short* hs16 = x16 + (size_t)MTOT * KD;                    // 32 MiB
    unsigned short* w16  = hs16 + (size_t)MTOT * HD;                   // 2 MiB: B,G,C,D
    unsigned long long* payload = (unsigned long long*)(w16 + (size_t)4 * HD * KD); // 1 MiB
    unsigned* flags = (unsigned*)(payload + (size_t)2048 * 64);        // 2049 u32

    cast_all<<<MTOT * KD / 1024 + 4 * (HD * KD / 1024), 256, 0, stream>>>(
        x, Bw, Wg, Cw, Dw, x16, w16, flags);

    in_gemm_scan<<<2048, 256, 0, stream>>>(
        (const short*)x16, (const short*)w16, Avec, bias_h, hs16, payload, flags);

    out_gemm_dual<<<dim3(MTOT / 128, HD / 128), 256, 0, stream>>>(
        (const short*)hs16, (const short*)x16,
        (const short*)(w16 + (size_t)2 * HD * KD),
        (const short*)(w16 + (size_t)3 * HD * KD), bias_y, y);
}